// Round 1
// baseline (653.560 us; speedup 1.0000x reference)
//
#include <hip/hip_runtime.h>

// ---------------------------------------------------------------------------
// RNN-T Joint Network, MI355X (gfx950)
//   f  = enc  @ W_enc^T   : [2048 x 640]   (B*T rows)
//   g  = pred @ W_pred^T  : [ 512 x 640]   (B*U1 rows)
//   out[b,t,u,v] = sum_j tanh(f[bt,j] + g[bu,j]) * W_out[v,j] + b_out[v]
// Big GEMM: M=131072, N=1024, K=640, fused tanh A-generation, fp16 MFMA.
// ---------------------------------------------------------------------------

typedef _Float16 f16x8 __attribute__((ext_vector_type(8)));
typedef float    f32x4 __attribute__((ext_vector_type(4)));

__device__ __forceinline__ float fast_tanh(float x) {
    // tanh(x) = 1 - 2/(exp2(2*log2(e)*x) + 1); v_exp + v_rcp, ~1ulp each.
    float e = __builtin_amdgcn_exp2f(x * 2.88539008177792681472f);
    return 1.0f - 2.0f * __builtin_amdgcn_rcpf(e + 1.0f);
}

// ---------------------------------------------------------------------------
// Kernel 1: fg GEMM (fp32, exact). Rows 0..2047 = enc @ W_enc^T,
// rows 2048..2559 = pred @ W_pred^T. K=512, N=640.
// Tile 64x64, BK=32, 256 threads, 4x4 per thread.
// ---------------------------------------------------------------------------
__global__ __launch_bounds__(256) void fg_kernel(
    const float* __restrict__ enc, const float* __restrict__ pred,
    const float* __restrict__ Wenc, const float* __restrict__ Wpred,
    float* __restrict__ fg)
{
    __shared__ float As[64][36];
    __shared__ float Ws[64][36];

    const int bid = blockIdx.x;          // 400 blocks
    const int mt = bid / 10;
    const int nt = bid % 10;
    const int m0 = mt * 64;
    const int n0 = nt * 64;

    const float* Aptr;
    const float* Wptr;
    if (m0 < 2048) { Aptr = enc  + (size_t)m0 * 512;          Wptr = Wenc; }
    else           { Aptr = pred + (size_t)(m0 - 2048) * 512; Wptr = Wpred; }

    const int t  = threadIdx.x;
    const int ty = t >> 4;          // 0..15
    const int tx = t & 15;          // 0..15
    const int lr = t >> 2;          // 0..63  (load row)
    const int lc = (t & 3) * 8;     // 0,8,16,24 (load col)

    float acc[4][4];
#pragma unroll
    for (int i = 0; i < 4; ++i)
#pragma unroll
        for (int j = 0; j < 4; ++j) acc[i][j] = 0.0f;

    for (int k0 = 0; k0 < 512; k0 += 32) {
        __syncthreads();
        {
            const float* sa = Aptr + (size_t)lr * 512 + k0 + lc;
            f32x4 a0 = *(const f32x4*)(sa);
            f32x4 a1 = *(const f32x4*)(sa + 4);
            *(f32x4*)&As[lr][lc]     = a0;
            *(f32x4*)&As[lr][lc + 4] = a1;
            const float* sw = Wptr + (size_t)(n0 + lr) * 512 + k0 + lc;
            f32x4 w0 = *(const f32x4*)(sw);
            f32x4 w1 = *(const f32x4*)(sw + 4);
            *(f32x4*)&Ws[lr][lc]     = w0;
            *(f32x4*)&Ws[lr][lc + 4] = w1;
        }
        __syncthreads();
#pragma unroll
        for (int kk = 0; kk < 32; ++kk) {
            float av[4], bv[4];
#pragma unroll
            for (int i = 0; i < 4; ++i) av[i] = As[ty * 4 + i][kk];
#pragma unroll
            for (int j = 0; j < 4; ++j) bv[j] = Ws[tx * 4 + j][kk];
#pragma unroll
            for (int i = 0; i < 4; ++i)
#pragma unroll
                for (int j = 0; j < 4; ++j)
                    acc[i][j] = fmaf(av[i], bv[j], acc[i][j]);
        }
    }

#pragma unroll
    for (int i = 0; i < 4; ++i) {
        f32x4 v = { acc[i][0], acc[i][1], acc[i][2], acc[i][3] };
        *(f32x4*)&fg[(size_t)(m0 + ty * 4 + i) * 640 + n0 + tx * 4] = v;
    }
}

// ---------------------------------------------------------------------------
// Kernel 2: W_out fp32 [1024][640] -> fp16, same layout (= B^T for MFMA).
// ---------------------------------------------------------------------------
__global__ __launch_bounds__(256) void wconv_kernel(
    const float* __restrict__ W, _Float16* __restrict__ Wh)
{
    const int idx = (blockIdx.x * 256 + threadIdx.x) * 8;  // 655360 elems total
    f32x4 a = *(const f32x4*)(W + idx);
    f32x4 b = *(const f32x4*)(W + idx + 4);
    f16x8 h;
#pragma unroll
    for (int j = 0; j < 4; ++j) { h[j] = (_Float16)a[j]; h[4 + j] = (_Float16)b[j]; }
    *(f16x8*)(Wh + idx) = h;
}

// ---------------------------------------------------------------------------
// Kernel 3: fused tanh + big GEMM.
// Grid: 1024 m-tiles x 4 n-tiles. Tile BM=128, BN=256, BK=32.
// 256 threads = 4 waves; each wave computes 64m x 128n (4x8 16x16 frags).
// A[m][k] = tanh(f[bt][k] + g[bu][k]) computed on the fly -> fp16 LDS.
// B from pre-converted fp16 W_out (already [n][k]).
// LDS rows padded to 40 f16 (80 B) -> 2-way (free) frag-read banks.
// ---------------------------------------------------------------------------
__global__ __launch_bounds__(256) void joint_kernel(
    const float* __restrict__ fg, const _Float16* __restrict__ Wh,
    const float* __restrict__ bias, float* __restrict__ out)
{
    __shared__ _Float16 Ash[128][40];
    __shared__ _Float16 Bsh[256][40];

    const int bid = blockIdx.x;      // 4096
    const int mt  = bid >> 2;        // n-tiles fastest: f/g rows stay L2-hot
    const int nt  = bid & 3;
    const int m0  = mt * 128;
    const int n0  = nt * 256;

    const int t    = threadIdx.x;
    const int lane = t & 63;
    const int wid  = t >> 6;
    const int wm   = wid & 1;        // m half (64 rows)
    const int wn   = wid >> 1;       // n half (128 cols)
    const int lrow = lane & 15;
    const int lk   = lane >> 4;      // 0..3 -> k = lk*8 + i

    // stage-A mapping: 2 threads per row, 16 k each
    const int mm = t >> 1;                 // 0..127
    const int kh = (t & 1) * 16;           // 0 / 16
    const int m  = m0 + mm;
    const float* frow = fg + (size_t)(m >> 6) * 640;
    const float* grow = fg + (size_t)(2048 + ((m >> 14) << 6) + (m & 63)) * 640;

    // stage-B mapping: 2 half-rows per thread (rows t>>1 and 128+(t>>1))
    const int bn = t >> 1;

    f32x4 acc[4][8];
#pragma unroll
    for (int i = 0; i < 4; ++i)
#pragma unroll
        for (int j = 0; j < 8; ++j) acc[i][j] = (f32x4){0.f, 0.f, 0.f, 0.f};

    for (int kc = 0; kc < 20; ++kc) {
        const int k0 = kc * 32;
        __syncthreads();

        // ---- stage A: h = tanh(f+g) -> fp16 LDS ----
        {
            const float* fp = frow + k0 + kh;
            const float* gp = grow + k0 + kh;
            f32x4 fv[4], gv[4];
#pragma unroll
            for (int q = 0; q < 4; ++q) {
                fv[q] = *(const f32x4*)(fp + q * 4);
                gv[q] = *(const f32x4*)(gp + q * 4);
            }
            f16x8 h0, h1;
#pragma unroll
            for (int q = 0; q < 2; ++q)
#pragma unroll
                for (int j = 0; j < 4; ++j)
                    h0[q * 4 + j] = (_Float16)fast_tanh(fv[q][j] + gv[q][j]);
#pragma unroll
            for (int q = 0; q < 2; ++q)
#pragma unroll
                for (int j = 0; j < 4; ++j)
                    h1[q * 4 + j] = (_Float16)fast_tanh(fv[2 + q][j] + gv[2 + q][j]);
            *(f16x8*)&Ash[mm][kh]     = h0;
            *(f16x8*)&Ash[mm][kh + 8] = h1;
        }

        // ---- stage B: W_out fp16 [n][k] -> LDS ----
#pragma unroll
        for (int half = 0; half < 2; ++half) {
            const int nn = bn + half * 128;
            const _Float16* src = Wh + (size_t)(n0 + nn) * 640 + k0 + kh;
            f16x8 b0 = *(const f16x8*)(src);
            f16x8 b1 = *(const f16x8*)(src + 8);
            *(f16x8*)&Bsh[nn][kh]     = b0;
            *(f16x8*)&Bsh[nn][kh + 8] = b1;
        }

        __syncthreads();

        // ---- fragments + MFMA ----
        f16x8 af[4], bf[8];
#pragma unroll
        for (int mf = 0; mf < 4; ++mf)
            af[mf] = *(const f16x8*)&Ash[wm * 64 + mf * 16 + lrow][lk * 8];
#pragma unroll
        for (int nf = 0; nf < 8; ++nf)
            bf[nf] = *(const f16x8*)&Bsh[wn * 128 + nf * 16 + lrow][lk * 8];
#pragma unroll
        for (int mf = 0; mf < 4; ++mf)
#pragma unroll
            for (int nf = 0; nf < 8; ++nf)
                acc[mf][nf] = __builtin_amdgcn_mfma_f32_16x16x32_f16(
                    af[mf], bf[nf], acc[mf][nf], 0, 0, 0);
    }

    // ---- epilogue: + bias, store fp32 ----
    float bv[8];
#pragma unroll
    for (int nf = 0; nf < 8; ++nf)
        bv[nf] = bias[n0 + wn * 128 + nf * 16 + lrow];

#pragma unroll
    for (int mf = 0; mf < 4; ++mf) {
#pragma unroll
        for (int r = 0; r < 4; ++r) {
            const int row = m0 + wm * 64 + mf * 16 + lk * 4 + r;
            float* orow = out + (size_t)row * 1024 + n0 + wn * 128;
#pragma unroll
            for (int nf = 0; nf < 8; ++nf)
                orow[nf * 16 + lrow] = acc[mf][nf][r] + bv[nf];
        }
    }
}

// ---------------------------------------------------------------------------
extern "C" void kernel_launch(void* const* d_in, const int* in_sizes, int n_in,
                              void* d_out, int out_size, void* d_ws, size_t ws_size,
                              hipStream_t stream) {
    const float* enc   = (const float*)d_in[0];   // [8,256,512]
    const float* pred  = (const float*)d_in[1];   // [8,64,512]
    const float* Wenc  = (const float*)d_in[2];   // [640,512]
    const float* Wpred = (const float*)d_in[3];   // [640,512]
    const float* Wout  = (const float*)d_in[4];   // [1024,640]
    const float* bout  = (const float*)d_in[5];   // [1024]

    float*     fg = (float*)d_ws;                             // 2560*640 fp32 = 6.25 MiB
    _Float16*  Wh = (_Float16*)((char*)d_ws + 2560 * 640 * 4); // 1024*640 fp16 = 1.25 MiB

    fg_kernel<<<400, 256, 0, stream>>>(enc, pred, Wenc, Wpred, fg);
    wconv_kernel<<<320, 256, 0, stream>>>(Wout, Wh);
    joint_kernel<<<4096, 256, 0, stream>>>(fg, Wh, bout, (float*)d_out);
}

// Round 2
// 477.177 us; speedup vs baseline: 1.3696x; 1.3696x over previous
//
#include <hip/hip_runtime.h>

// ---------------------------------------------------------------------------
// RNN-T Joint Network, MI355X (gfx950)
//   f  = enc  @ W_enc^T   : [2048 x 640]   (B*T rows)
//   g  = pred @ W_pred^T  : [ 512 x 640]   (B*U1 rows)
//   out[b,t,u,v] = sum_j tanh(f[bt,j] + g[bu,j]) * W_out[v,j] + b_out[v]
// Big GEMM: M=131072, N=1024, K=640. Key fact: a 256-row m-tile spans only
// 4 distinct f-rows and 64 distinct g-rows (u fastest) -> stage is cheap.
// ---------------------------------------------------------------------------

typedef _Float16 f16x8 __attribute__((ext_vector_type(8)));
typedef float    f32x4 __attribute__((ext_vector_type(4)));

__device__ __forceinline__ float fast_tanh(float x) {
    float e = __builtin_amdgcn_exp2f(x * 2.88539008177792681472f);
    return 1.0f - 2.0f * __builtin_amdgcn_rcpf(e + 1.0f);
}

__device__ __forceinline__ void gll16(const void* g, void* l) {
    __builtin_amdgcn_global_load_lds(
        (const __attribute__((address_space(1))) void*)g,
        (__attribute__((address_space(3))) void*)l, 16, 0, 0);
}

// ---------------------------------------------------------------------------
// Kernel 1: fg GEMM (fp32, exact). Rows 0..2047 = enc @ W_enc^T,
// rows 2048..2559 = pred @ W_pred^T. K=512, tile 64x64, BK=32.
// ---------------------------------------------------------------------------
__global__ __launch_bounds__(256) void fg_kernel(
    const float* __restrict__ enc, const float* __restrict__ pred,
    const float* __restrict__ Wenc, const float* __restrict__ Wpred,
    float* __restrict__ fg)
{
    __shared__ float As[64][36];
    __shared__ float Ws[64][36];

    const int bid = blockIdx.x;          // 400 blocks
    const int mt = bid / 10;
    const int nt = bid % 10;
    const int m0 = mt * 64;
    const int n0 = nt * 64;

    const float* Aptr;
    const float* Wptr;
    if (m0 < 2048) { Aptr = enc  + (size_t)m0 * 512;          Wptr = Wenc; }
    else           { Aptr = pred + (size_t)(m0 - 2048) * 512; Wptr = Wpred; }

    const int t  = threadIdx.x;
    const int ty = t >> 4;
    const int tx = t & 15;
    const int lr = t >> 2;
    const int lc = (t & 3) * 8;

    float acc[4][4];
#pragma unroll
    for (int i = 0; i < 4; ++i)
#pragma unroll
        for (int j = 0; j < 4; ++j) acc[i][j] = 0.0f;

    for (int k0 = 0; k0 < 512; k0 += 32) {
        __syncthreads();
        {
            const float* sa = Aptr + (size_t)lr * 512 + k0 + lc;
            f32x4 a0 = *(const f32x4*)(sa);
            f32x4 a1 = *(const f32x4*)(sa + 4);
            *(f32x4*)&As[lr][lc]     = a0;
            *(f32x4*)&As[lr][lc + 4] = a1;
            const float* sw = Wptr + (size_t)(n0 + lr) * 512 + k0 + lc;
            f32x4 w0 = *(const f32x4*)(sw);
            f32x4 w1 = *(const f32x4*)(sw + 4);
            *(f32x4*)&Ws[lr][lc]     = w0;
            *(f32x4*)&Ws[lr][lc + 4] = w1;
        }
        __syncthreads();
#pragma unroll
        for (int kk = 0; kk < 32; ++kk) {
            float av[4], bv[4];
#pragma unroll
            for (int i = 0; i < 4; ++i) av[i] = As[ty * 4 + i][kk];
#pragma unroll
            for (int j = 0; j < 4; ++j) bv[j] = Ws[tx * 4 + j][kk];
#pragma unroll
            for (int i = 0; i < 4; ++i)
#pragma unroll
                for (int j = 0; j < 4; ++j)
                    acc[i][j] = fmaf(av[i], bv[j], acc[i][j]);
        }
    }

#pragma unroll
    for (int i = 0; i < 4; ++i) {
        f32x4 v = { acc[i][0], acc[i][1], acc[i][2], acc[i][3] };
        *(f32x4*)&fg[(size_t)(m0 + ty * 4 + i) * 640 + n0 + tx * 4] = v;
    }
}

// ---------------------------------------------------------------------------
// Kernel 2: W_out fp32 [1024][640] -> fp16 same layout.
// ---------------------------------------------------------------------------
__global__ __launch_bounds__(256) void wconv_kernel(
    const float* __restrict__ W, _Float16* __restrict__ Wh)
{
    const int idx = (blockIdx.x * 256 + threadIdx.x) * 8;
    f32x4 a = *(const f32x4*)(W + idx);
    f32x4 b = *(const f32x4*)(W + idx + 4);
    f16x8 h;
#pragma unroll
    for (int j = 0; j < 4; ++j) { h[j] = (_Float16)a[j]; h[4 + j] = (_Float16)b[j]; }
    *(f16x8*)(Wh + idx) = h;
}

// ---------------------------------------------------------------------------
// Kernel 3: fused tanh + big GEMM.  BM=256, BN=256, BK=64, 512 thr = 8 waves
// (2m x 4n), per-wave 128m x 64n = 8x4 16x16x32 frags, acc 128 VGPR.
// LDS (single-buffered, 74 KB): Ash 32K (swizzled), Bsh 32K (swizzled via
// pre-swizzled gll source), fsh 10K (4 f-rows, hoisted out of K-loop).
// Swizzle: 16B-chunk index (0..7 per 128B row) ^= (row & 7)  -> frag reads
// are 2-way (free) instead of 16-way conflicted.
// ---------------------------------------------------------------------------
__global__ __launch_bounds__(512, 2) void joint_kernel(
    const float* __restrict__ fg, const _Float16* __restrict__ Wh,
    const float* __restrict__ bias, float* __restrict__ out)
{
    __shared__ _Float16 Ash[256 * 64];   // [row][k] swizzled, 32 KB
    __shared__ _Float16 Bsh[256 * 64];   // [row][k] swizzled, 32 KB
    __shared__ float    fsh[4 * 640];    // f rows for this m-tile, 10 KB

    const int bid = blockIdx.x;          // 2048
    const int mt  = bid >> 2;            // n fastest -> fg rows L2-hot
    const int nt  = bid & 3;
    const int m0  = mt << 8;
    const int n0  = nt << 8;

    const int t    = threadIdx.x;
    const int lane = t & 63;
    const int wid  = t >> 6;
    const int wm   = wid & 1;            // 0..1 : m half (128 rows)
    const int wn   = wid >> 1;           // 0..3 : n quarter (64 cols)
    const int lr   = lane & 15;
    const int lk   = lane >> 4;          // 0..3

    // ---- preload f-block: fg rows m0/64 .. +3 (4 x 640 fp32) ----
    {
        const float* fbase = fg + (size_t)(m0 >> 6) * 640;
#pragma unroll
        for (int i = t; i < 640; i += 512)
            *(f32x4*)&fsh[i * 4] = *(const f32x4*)(fbase + i * 4);
    }

    // ---- stage-A mapping: thread t -> A row r = t>>1, k-half (t&1)*32 ----
    const int r   = t >> 1;              // 0..255
    const int kh  = t & 1;               // which 32-k half
    const int fro = (r >> 6) * 640;      // f row offset in fsh
    const float* grow = fg + (size_t)(2048 + ((m0 >> 14) << 6) + (r & 63)) * 640
                        + kh * 32;
    const int aswz = ((kh * 4) /*chunk base*/);

    f32x4 acc[8][4];
#pragma unroll
    for (int i = 0; i < 8; ++i)
#pragma unroll
        for (int j = 0; j < 4; ++j) acc[i][j] = (f32x4){0.f, 0.f, 0.f, 0.f};

    for (int kc = 0; kc < 10; ++kc) {
        const int k0 = kc * 64;
        __syncthreads();   // prev MFMA done reading LDS (and fsh ready, iter 0)

        // ---- B: global_load_lds, pre-swizzled source ----
        {
#pragma unroll
            for (int is = 0; is < 4; ++is) {
                const int orow   = wid * 32 + is * 8 + (lane >> 3);
                const int schunk = (lane & 7) ^ (orow & 7);
                const _Float16* src =
                    Wh + (size_t)(n0 + orow) * 640 + k0 + schunk * 8;
                gll16(src, &Bsh[wid * 2048 + is * 512]);
            }
        }

        // ---- A: g regs + f LDS -> tanh -> swizzled ds_write ----
        {
            const float* gp = grow + k0;
            const float* fp = &fsh[fro + k0 + kh * 32];
            f32x4 gv[8], fv[8];
#pragma unroll
            for (int c = 0; c < 8; ++c) gv[c] = *(const f32x4*)(gp + c * 4);
#pragma unroll
            for (int c = 0; c < 8; ++c) fv[c] = *(const f32x4*)(fp + c * 4);
#pragma unroll
            for (int c = 0; c < 4; ++c) {
                f16x8 h;
#pragma unroll
                for (int j = 0; j < 8; ++j) {
                    const int e = c * 2 + (j >> 2);
                    h[j] = (_Float16)fast_tanh(fv[e][j & 3] + gv[e][j & 3]);
                }
                const int swz = (aswz + c) ^ (r & 7);
                *(f16x8*)&Ash[r * 64 + swz * 8] = h;
            }
        }

        __syncthreads();   // A visible; barrier drains vmcnt -> B landed

        // ---- fragments + MFMA ----
#pragma unroll
        for (int kf = 0; kf < 2; ++kf) {
            f16x8 af[8], bf[4];
#pragma unroll
            for (int mf = 0; mf < 8; ++mf) {
                const int row = wm * 128 + mf * 16 + lr;
                const int swz = (kf * 4 + lk) ^ (row & 7);
                af[mf] = *(const f16x8*)&Ash[row * 64 + swz * 8];
            }
#pragma unroll
            for (int nf = 0; nf < 4; ++nf) {
                const int row = wn * 64 + nf * 16 + lr;
                const int swz = (kf * 4 + lk) ^ (row & 7);
                bf[nf] = *(const f16x8*)&Bsh[row * 64 + swz * 8];
            }
#pragma unroll
            for (int mf = 0; mf < 8; ++mf)
#pragma unroll
                for (int nf = 0; nf < 4; ++nf)
                    acc[mf][nf] = __builtin_amdgcn_mfma_f32_16x16x32_f16(
                        af[mf], bf[nf], acc[mf][nf], 0, 0, 0);
        }
    }

    // ---- epilogue: + bias, store fp32 ----
    float bv[4];
#pragma unroll
    for (int nf = 0; nf < 4; ++nf)
        bv[nf] = bias[n0 + wn * 64 + nf * 16 + lr];

#pragma unroll
    for (int mf = 0; mf < 8; ++mf) {
#pragma unroll
        for (int rr = 0; rr < 4; ++rr) {
            const int row = m0 + wm * 128 + mf * 16 + lk * 4 + rr;
            float* orow = out + (size_t)row * 1024 + n0 + wn * 64;
#pragma unroll
            for (int nf = 0; nf < 4; ++nf)
                orow[nf * 16 + lr] = acc[mf][nf][rr] + bv[nf];
        }
    }
}

// ---------------------------------------------------------------------------
extern "C" void kernel_launch(void* const* d_in, const int* in_sizes, int n_in,
                              void* d_out, int out_size, void* d_ws, size_t ws_size,
                              hipStream_t stream) {
    const float* enc   = (const float*)d_in[0];   // [8,256,512]
    const float* pred  = (const float*)d_in[1];   // [8,64,512]
    const float* Wenc  = (const float*)d_in[2];   // [640,512]
    const float* Wpred = (const float*)d_in[3];   // [640,512]
    const float* Wout  = (const float*)d_in[4];   // [1024,640]
    const float* bout  = (const float*)d_in[5];   // [1024]

    float*     fg = (float*)d_ws;                              // 2560*640 fp32
    _Float16*  Wh = (_Float16*)((char*)d_ws + 2560 * 640 * 4); // 1024*640 fp16

    fg_kernel<<<400, 256, 0, stream>>>(enc, pred, Wenc, Wpred, fg);
    wconv_kernel<<<320, 256, 0, stream>>>(Wout, Wh);
    joint_kernel<<<2048, 512, 0, stream>>>(fg, Wh, bout, (float*)d_out);
}

// Round 3
// 402.992 us; speedup vs baseline: 1.6218x; 1.1841x over previous
//
#include <hip/hip_runtime.h>

// ---------------------------------------------------------------------------
// RNN-T Joint Network, MI355X (gfx950)
//   f  = enc  @ W_enc^T   : [2048 x 640]   (B*T rows)
//   g  = pred @ W_pred^T  : [ 512 x 640]   (B*U1 rows)
//   out[b,t,u,v] = sum_j tanh(f[bt,j] + g[bu,j]) * W_out[v,j] + b_out[v]
// Joint GEMM: M=131072, N=1024, K=640, A=tanh(f+g) generated on the fly.
// R3: BM=128 x BN=512 x BK=32, double-buffered LDS, 1 barrier/K-step,
//     tanh redundancy 2x (was 4x), B staged via global_load_lds.
// ---------------------------------------------------------------------------

typedef _Float16 f16x8 __attribute__((ext_vector_type(8)));
typedef float    f32x4 __attribute__((ext_vector_type(4)));

__device__ __forceinline__ float fast_tanh(float x) {
    float e = __builtin_amdgcn_exp2f(x * 2.88539008177792681472f);
    return 1.0f - 2.0f * __builtin_amdgcn_rcpf(e + 1.0f);
}

__device__ __forceinline__ void gll16(const void* g, void* l) {
    __builtin_amdgcn_global_load_lds(
        (const __attribute__((address_space(1))) void*)g,
        (__attribute__((address_space(3))) void*)l, 16, 0, 0);
}

// ---------------------------------------------------------------------------
// Kernel 1: fg GEMM (fp32, exact). Rows 0..2047 = enc @ W_enc^T,
// rows 2048..2559 = pred @ W_pred^T. K=512, tile 64x64, BK=32.
// ---------------------------------------------------------------------------
__global__ __launch_bounds__(256) void fg_kernel(
    const float* __restrict__ enc, const float* __restrict__ pred,
    const float* __restrict__ Wenc, const float* __restrict__ Wpred,
    float* __restrict__ fg)
{
    __shared__ float As[64][36];
    __shared__ float Ws[64][36];

    const int bid = blockIdx.x;
    const int mt = bid / 10;
    const int nt = bid % 10;
    const int m0 = mt * 64;
    const int n0 = nt * 64;

    const float* Aptr;
    const float* Wptr;
    if (m0 < 2048) { Aptr = enc  + (size_t)m0 * 512;          Wptr = Wenc; }
    else           { Aptr = pred + (size_t)(m0 - 2048) * 512; Wptr = Wpred; }

    const int t  = threadIdx.x;
    const int ty = t >> 4;
    const int tx = t & 15;
    const int lr = t >> 2;
    const int lc = (t & 3) * 8;

    float acc[4][4];
#pragma unroll
    for (int i = 0; i < 4; ++i)
#pragma unroll
        for (int j = 0; j < 4; ++j) acc[i][j] = 0.0f;

    for (int k0 = 0; k0 < 512; k0 += 32) {
        __syncthreads();
        {
            const float* sa = Aptr + (size_t)lr * 512 + k0 + lc;
            f32x4 a0 = *(const f32x4*)(sa);
            f32x4 a1 = *(const f32x4*)(sa + 4);
            *(f32x4*)&As[lr][lc]     = a0;
            *(f32x4*)&As[lr][lc + 4] = a1;
            const float* sw = Wptr + (size_t)(n0 + lr) * 512 + k0 + lc;
            f32x4 w0 = *(const f32x4*)(sw);
            f32x4 w1 = *(const f32x4*)(sw + 4);
            *(f32x4*)&Ws[lr][lc]     = w0;
            *(f32x4*)&Ws[lr][lc + 4] = w1;
        }
        __syncthreads();
#pragma unroll
        for (int kk = 0; kk < 32; ++kk) {
            float av[4], bv[4];
#pragma unroll
            for (int i = 0; i < 4; ++i) av[i] = As[ty * 4 + i][kk];
#pragma unroll
            for (int j = 0; j < 4; ++j) bv[j] = Ws[tx * 4 + j][kk];
#pragma unroll
            for (int i = 0; i < 4; ++i)
#pragma unroll
                for (int j = 0; j < 4; ++j)
                    acc[i][j] = fmaf(av[i], bv[j], acc[i][j]);
        }
    }

#pragma unroll
    for (int i = 0; i < 4; ++i) {
        f32x4 v = { acc[i][0], acc[i][1], acc[i][2], acc[i][3] };
        *(f32x4*)&fg[(size_t)(m0 + ty * 4 + i) * 640 + n0 + tx * 4] = v;
    }
}

// ---------------------------------------------------------------------------
// Kernel 2: W_out fp32 [1024][640] -> fp16 same layout.
// ---------------------------------------------------------------------------
__global__ __launch_bounds__(256) void wconv_kernel(
    const float* __restrict__ W, _Float16* __restrict__ Wh)
{
    const int idx = (blockIdx.x * 256 + threadIdx.x) * 8;
    f32x4 a = *(const f32x4*)(W + idx);
    f32x4 b = *(const f32x4*)(W + idx + 4);
    f16x8 h;
#pragma unroll
    for (int j = 0; j < 4; ++j) { h[j] = (_Float16)a[j]; h[4 + j] = (_Float16)b[j]; }
    *(f16x8*)(Wh + idx) = h;
}

// ---------------------------------------------------------------------------
// Kernel 3: fused tanh + big GEMM.
// BM=128, BN=512, BK=32, 512 thr = 8 waves (2m x 4n), wave tile 64m x 128n
// (4x8 frags, 128 acc regs -> AGPR). LDS: A 2x8KB + B 2x32KB = 80KB, double
// buffered, ONE barrier per K-step (stage kc+1 in shadow of MFMA kc).
// Swizzle (both sides): 16B-slot = chunk ^ (row&3) ^ ((row>>2)&3).
// ---------------------------------------------------------------------------
__global__ __launch_bounds__(512, 2) void joint_kernel(
    const float* __restrict__ fg, const _Float16* __restrict__ Wh,
    const float* __restrict__ bias, float* __restrict__ out)
{
    __shared__ _Float16 Ash[2][128 * 32];   // 2 x 8 KB, swizzled
    __shared__ _Float16 Bsh[2][512 * 32];   // 2 x 32 KB, swizzled

    const int bid = blockIdx.x;            // 2048
    const int mt  = bid >> 1;              // n fastest
    const int nt  = bid & 1;
    const int m0  = mt << 7;
    const int n0  = nt << 9;

    const int t    = threadIdx.x;
    const int lane = t & 63;
    const int wid  = t >> 6;
    const int wm   = wid & 1;              // m half (64 rows)
    const int wn   = wid >> 1;             // n quarter (128 cols)
    const int lr   = lane & 15;
    const int lk   = lane >> 4;            // 0..3 (k-chunk of 8)

    // stage-A mapping: 4 threads per row, 8 k each
    const int r  = t >> 2;                 // 0..127
    const int q  = t & 3;                  // k-chunk
    const int m  = m0 + r;
    const float* grow = fg + (size_t)(2048 + ((m >> 14) << 6) + (m & 63)) * 640;
    const float* frow = fg + (size_t)(m >> 6) * 640;
    const int aslot = q ^ (r & 3) ^ ((r >> 2) & 3);

    f32x4 acc[4][8];
#pragma unroll
    for (int i = 0; i < 4; ++i)
#pragma unroll
        for (int j = 0; j < 8; ++j) acc[i][j] = (f32x4){0.f, 0.f, 0.f, 0.f};

    auto stage = [&](int k0, int buf) {
        // ---- B: 4 x global_load_lds (16B/lane), inverse-swizzled source ----
#pragma unroll
        for (int i = 0; i < 4; ++i) {
            const int seg = wid * 4 + i;             // 1 KB segment = 16 rows
            const int row = (seg << 4) + (lane >> 2);
            const int c   = (lane & 3) ^ (row & 3) ^ ((row >> 2) & 3);
            gll16(Wh + (size_t)(n0 + row) * 640 + k0 + c * 8,
                  &Bsh[buf][seg << 9]);
        }
        // ---- A: tanh(f+g) -> swizzled ds_write ----
        {
            const float* gp = grow + k0 + q * 8;
            const float* fp = frow + k0 + q * 8;
            f32x4 g0 = *(const f32x4*)(gp);
            f32x4 g1 = *(const f32x4*)(gp + 4);
            f32x4 f0 = *(const f32x4*)(fp);
            f32x4 f1 = *(const f32x4*)(fp + 4);
            f16x8 h;
#pragma unroll
            for (int j = 0; j < 4; ++j) {
                h[j]     = (_Float16)fast_tanh(f0[j] + g0[j]);
                h[4 + j] = (_Float16)fast_tanh(f1[j] + g1[j]);
            }
            *(f16x8*)&Ash[buf][r * 32 + aslot * 8] = h;
        }
    };

    auto compute = [&](int buf) {
        f16x8 af[4], bf[8];
#pragma unroll
        for (int mf = 0; mf < 4; ++mf) {
            const int row  = wm * 64 + mf * 16 + lr;
            const int slot = lk ^ (row & 3) ^ ((row >> 2) & 3);
            af[mf] = *(const f16x8*)&Ash[buf][row * 32 + slot * 8];
        }
#pragma unroll
        for (int nf = 0; nf < 8; ++nf) {
            const int row  = wn * 128 + nf * 16 + lr;
            const int slot = lk ^ (row & 3) ^ ((row >> 2) & 3);
            bf[nf] = *(const f16x8*)&Bsh[buf][row * 32 + slot * 8];
        }
#pragma unroll
        for (int mf = 0; mf < 4; ++mf)
#pragma unroll
            for (int nf = 0; nf < 8; ++nf)
                acc[mf][nf] = __builtin_amdgcn_mfma_f32_16x16x32_f16(
                    af[mf], bf[nf], acc[mf][nf], 0, 0, 0);
    };

    stage(0, 0);
    __syncthreads();
    for (int kc = 0; kc < 19; ++kc) {
        stage((kc + 1) * 32, (kc + 1) & 1);   // fills buf^1 while MFMA eats buf
        compute(kc & 1);
        __syncthreads();                       // drains vmcnt+lgkm; flips buffers
    }
    compute(1);                                // kc = 19

    // ---- epilogue: + bias, store fp32 ----
    float bv[8];
#pragma unroll
    for (int nf = 0; nf < 8; ++nf)
        bv[nf] = bias[n0 + wn * 128 + nf * 16 + lr];

#pragma unroll
    for (int mf = 0; mf < 4; ++mf) {
#pragma unroll
        for (int rr = 0; rr < 4; ++rr) {
            const int row = m0 + wm * 64 + mf * 16 + lk * 4 + rr;
            float* orow = out + (size_t)row * 1024 + n0 + wn * 128;
#pragma unroll
            for (int nf = 0; nf < 8; ++nf)
                orow[nf * 16 + lr] = acc[mf][nf][rr] + bv[nf];
        }
    }
}

// ---------------------------------------------------------------------------
extern "C" void kernel_launch(void* const* d_in, const int* in_sizes, int n_in,
                              void* d_out, int out_size, void* d_ws, size_t ws_size,
                              hipStream_t stream) {
    const float* enc   = (const float*)d_in[0];   // [8,256,512]
    const float* pred  = (const float*)d_in[1];   // [8,64,512]
    const float* Wenc  = (const float*)d_in[2];   // [640,512]
    const float* Wpred = (const float*)d_in[3];   // [640,512]
    const float* Wout  = (const float*)d_in[4];   // [1024,640]
    const float* bout  = (const float*)d_in[5];   // [1024]

    float*     fg = (float*)d_ws;                              // 2560*640 fp32
    _Float16*  Wh = (_Float16*)((char*)d_ws + 2560 * 640 * 4); // 1024*640 fp16

    fg_kernel<<<400, 256, 0, stream>>>(enc, pred, Wenc, Wpred, fg);
    wconv_kernel<<<320, 256, 0, stream>>>(Wout, Wh);
    joint_kernel<<<2048, 512, 0, stream>>>(fg, Wh, bout, (float*)d_out);
}

// Round 4
// 304.126 us; speedup vs baseline: 2.1490x; 1.3251x over previous
//
#include <hip/hip_runtime.h>

// ---------------------------------------------------------------------------
// RNN-T Joint Network, MI355X (gfx950)
//   f  = enc  @ W_enc^T   : [2048 x 640]
//   g  = pred @ W_pred^T  : [ 512 x 640]
//   out[b,t,u,v] = sum_j tanh(f[bt,j] + g[bu,j]) * W_out[v,j] + b_out[v]
// R4: dataflow-ordered pipeline, distinct LDS buffers (alias-analysis-
// friendly), A padded stride-40 (no swizzle), XCD-chunked block swizzle.
// ---------------------------------------------------------------------------

typedef _Float16 f16x8 __attribute__((ext_vector_type(8)));
typedef float    f32x4 __attribute__((ext_vector_type(4)));

__device__ __forceinline__ float fast_tanh(float x) {
    float e = __builtin_amdgcn_exp2f(x * 2.88539008177792681472f);
    return 1.0f - 2.0f * __builtin_amdgcn_rcpf(e + 1.0f);
}

__device__ __forceinline__ void gll16(const void* g, void* l) {
    __builtin_amdgcn_global_load_lds(
        (const __attribute__((address_space(1))) void*)g,
        (__attribute__((address_space(3))) void*)l, 16, 0, 0);
}

// ---------------------------------------------------------------------------
// Kernel 1: fg GEMM (fp32, exact). W staged transposed -> broadcast reads.
// ---------------------------------------------------------------------------
__global__ __launch_bounds__(256) void fg_kernel(
    const float* __restrict__ enc, const float* __restrict__ pred,
    const float* __restrict__ Wenc, const float* __restrict__ Wpred,
    float* __restrict__ fg)
{
    __shared__ float As[64][36];
    __shared__ float WsT[32][68];   // [k][n], pad 68: bv reads broadcast-free

    const int bid = blockIdx.x;
    const int mt = bid / 10;
    const int nt = bid % 10;
    const int m0 = mt * 64;
    const int n0 = nt * 64;

    const float* Aptr;
    const float* Wptr;
    if (m0 < 2048) { Aptr = enc  + (size_t)m0 * 512;          Wptr = Wenc; }
    else           { Aptr = pred + (size_t)(m0 - 2048) * 512; Wptr = Wpred; }

    const int t  = threadIdx.x;
    const int ty = t >> 4;
    const int tx = t & 15;
    const int lr = t >> 2;
    const int lc = (t & 3) * 8;
    const int lane6 = t & 63;
    const int w8    = (t >> 6) * 8;    // wave w stages k-rows w*8..w*8+7

    float acc[4][4];
#pragma unroll
    for (int i = 0; i < 4; ++i)
#pragma unroll
        for (int j = 0; j < 4; ++j) acc[i][j] = 0.0f;

    for (int k0 = 0; k0 < 512; k0 += 32) {
        __syncthreads();
        {
            const float* sa = Aptr + (size_t)lr * 512 + k0 + lc;
            f32x4 a0 = *(const f32x4*)(sa);
            f32x4 a1 = *(const f32x4*)(sa + 4);
            *(f32x4*)&As[lr][lc]     = a0;
            *(f32x4*)&As[lr][lc + 4] = a1;
            const float* sw = Wptr + (size_t)(n0 + lane6) * 512 + k0 + w8;
            f32x4 w0 = *(const f32x4*)(sw);
            f32x4 w1 = *(const f32x4*)(sw + 4);
#pragma unroll
            for (int j = 0; j < 4; ++j) {
                WsT[w8 + j][lane6]     = w0[j];
                WsT[w8 + 4 + j][lane6] = w1[j];
            }
        }
        __syncthreads();
#pragma unroll
        for (int kk = 0; kk < 32; ++kk) {
            float av[4], bv[4];
#pragma unroll
            for (int i = 0; i < 4; ++i) av[i] = As[ty * 4 + i][kk];
#pragma unroll
            for (int j = 0; j < 4; ++j) bv[j] = WsT[kk][tx * 4 + j];
#pragma unroll
            for (int i = 0; i < 4; ++i)
#pragma unroll
                for (int j = 0; j < 4; ++j)
                    acc[i][j] = fmaf(av[i], bv[j], acc[i][j]);
        }
    }

#pragma unroll
    for (int i = 0; i < 4; ++i) {
        f32x4 v = { acc[i][0], acc[i][1], acc[i][2], acc[i][3] };
        *(f32x4*)&fg[(size_t)(m0 + ty * 4 + i) * 640 + n0 + tx * 4] = v;
    }
}

// ---------------------------------------------------------------------------
// Kernel 2: W_out fp32 [1024][640] -> fp16 same layout.
// ---------------------------------------------------------------------------
__global__ __launch_bounds__(256) void wconv_kernel(
    const float* __restrict__ W, _Float16* __restrict__ Wh)
{
    const int idx = (blockIdx.x * 256 + threadIdx.x) * 8;
    f32x4 a = *(const f32x4*)(W + idx);
    f32x4 b = *(const f32x4*)(W + idx + 4);
    f16x8 h;
#pragma unroll
    for (int j = 0; j < 4; ++j) { h[j] = (_Float16)a[j]; h[4 + j] = (_Float16)b[j]; }
    *(f16x8*)(Wh + idx) = h;
}

// ---------------------------------------------------------------------------
// Kernel 3: fused tanh + big GEMM.  BM=128, BN=512, BK=32, 512 thr = 8 waves
// (2m x 4n), wave 64m x 128n (4x8 frags). Distinct double buffers; per-iter
// order: gll B(next) -> f/g loads(next) -> frag reads(cur) -> MFMA(cur)
// -> tanh+ds_write A(next) -> syncthreads.
// Ash: padded stride 40 (16B-aligned, 2-way-free reads, no swizzle).
// Bsh: 32/row, XOR swizzle slot = c ^ (row&3) ^ ((row>>2)&3), pre-swizzled
// gll source (both-sides rule).
// ---------------------------------------------------------------------------
__global__ __launch_bounds__(512, 2) void joint_kernel(
    const float* __restrict__ fg, const _Float16* __restrict__ Wh,
    const float* __restrict__ bias, float* __restrict__ out)
{
    __shared__ _Float16 Ash0[128 * 40];
    __shared__ _Float16 Ash1[128 * 40];
    __shared__ _Float16 Bsh0[512 * 32];
    __shared__ _Float16 Bsh1[512 * 32];

    const int bid = blockIdx.x;            // 2048
    const int pp  = bid >> 1;              // 1024 m-tiles
    const int mt  = (pp & 7) * 128 + (pp >> 3);   // XCD-chunked (bijective)
    const int nt  = bid & 1;
    const int m0  = mt << 7;
    const int n0  = nt << 9;

    const int t    = threadIdx.x;
    const int lane = t & 63;
    const int wid  = t >> 6;
    const int wm   = wid & 1;
    const int wn   = wid >> 1;
    const int lr   = lane & 15;
    const int lk   = lane >> 4;

    // stage-A mapping: 4 threads per row, 8 k each
    const int r  = t >> 2;                 // 0..127
    const int q  = t & 3;
    const int m  = m0 + r;
    const float* grow = fg + (size_t)(2048 + ((m >> 14) << 6) + (m & 63)) * 640;
    const float* frow = fg + (size_t)(m >> 6) * 640;

    f32x4 acc[4][8];
#pragma unroll
    for (int i = 0; i < 4; ++i)
#pragma unroll
        for (int j = 0; j < 8; ++j) acc[i][j] = (f32x4){0.f, 0.f, 0.f, 0.f};

    // ---- prologue: stage k-range 0 into Ash0/Bsh0 ----
    {
#pragma unroll
        for (int i = 0; i < 4; ++i) {
            const int seg = wid * 4 + i;
            const int row = (seg << 4) + (lane >> 2);
            const int c   = (lane & 3) ^ (row & 3) ^ ((row >> 2) & 3);
            gll16(Wh + (size_t)(n0 + row) * 640 + c * 8, &Bsh0[seg << 9]);
        }
        f32x4 fv0 = *(const f32x4*)(frow + q * 8);
        f32x4 fv1 = *(const f32x4*)(frow + q * 8 + 4);
        f32x4 gv0 = *(const f32x4*)(grow + q * 8);
        f32x4 gv1 = *(const f32x4*)(grow + q * 8 + 4);
        f16x8 h;
#pragma unroll
        for (int j = 0; j < 4; ++j) {
            h[j]     = (_Float16)fast_tanh(fv0[j] + gv0[j]);
            h[4 + j] = (_Float16)fast_tanh(fv1[j] + gv1[j]);
        }
        *(f16x8*)&Ash0[r * 40 + q * 8] = h;
        __syncthreads();
    }

#define JITER_FULL(K0, CA, CB, NA, NB)                                         \
    {                                                                          \
        const int kn_ = (K0) + 32;                                             \
        _Pragma("unroll")                                                      \
        for (int i = 0; i < 4; ++i) {                                          \
            const int seg = wid * 4 + i;                                       \
            const int brow = (seg << 4) + (lane >> 2);                         \
            const int c    = (lane & 3) ^ (brow & 3) ^ ((brow >> 2) & 3);      \
            gll16(Wh + (size_t)(n0 + brow) * 640 + kn_ + c * 8,                \
                  &NB[seg << 9]);                                              \
        }                                                                      \
        f32x4 fv0_ = *(const f32x4*)(frow + kn_ + q * 8);                      \
        f32x4 fv1_ = *(const f32x4*)(frow + kn_ + q * 8 + 4);                  \
        f32x4 gv0_ = *(const f32x4*)(grow + kn_ + q * 8);                      \
        f32x4 gv1_ = *(const f32x4*)(grow + kn_ + q * 8 + 4);                  \
        f16x8 af[4], bf[8];                                                    \
        _Pragma("unroll")                                                      \
        for (int mf = 0; mf < 4; ++mf) {                                       \
            const int arow = wm * 64 + mf * 16 + lr;                           \
            af[mf] = *(const f16x8*)&CA[arow * 40 + lk * 8];                   \
        }                                                                      \
        _Pragma("unroll")                                                      \
        for (int nf = 0; nf < 8; ++nf) {                                       \
            const int brow = wn * 128 + nf * 16 + lr;                          \
            const int slot = lk ^ (brow & 3) ^ ((brow >> 2) & 3);              \
            bf[nf] = *(const f16x8*)&CB[brow * 32 + slot * 8];                 \
        }                                                                      \
        __builtin_amdgcn_s_setprio(1);                                         \
        _Pragma("unroll")                                                      \
        for (int mf = 0; mf < 4; ++mf)                                         \
            _Pragma("unroll")                                                  \
            for (int nf = 0; nf < 8; ++nf)                                     \
                acc[mf][nf] = __builtin_amdgcn_mfma_f32_16x16x32_f16(          \
                    af[mf], bf[nf], acc[mf][nf], 0, 0, 0);                     \
        __builtin_amdgcn_s_setprio(0);                                         \
        {                                                                      \
            f16x8 h;                                                           \
            _Pragma("unroll")                                                  \
            for (int j = 0; j < 4; ++j) {                                      \
                h[j]     = (_Float16)fast_tanh(fv0_[j] + gv0_[j]);             \
                h[4 + j] = (_Float16)fast_tanh(fv1_[j] + gv1_[j]);             \
            }                                                                  \
            *(f16x8*)&NA[r * 40 + q * 8] = h;                                  \
        }                                                                      \
        __syncthreads();                                                       \
    }

#define JITER_LAST(CA, CB)                                                     \
    {                                                                          \
        f16x8 af[4], bf[8];                                                    \
        _Pragma("unroll")                                                      \
        for (int mf = 0; mf < 4; ++mf) {                                       \
            const int arow = wm * 64 + mf * 16 + lr;                           \
            af[mf] = *(const f16x8*)&CA[arow * 40 + lk * 8];                   \
        }                                                                      \
        _Pragma("unroll")                                                      \
        for (int nf = 0; nf < 8; ++nf) {                                       \
            const int brow = wn * 128 + nf * 16 + lr;                          \
            const int slot = lk ^ (brow & 3) ^ ((brow >> 2) & 3);              \
            bf[nf] = *(const f16x8*)&CB[brow * 32 + slot * 8];                 \
        }                                                                      \
        __builtin_amdgcn_s_setprio(1);                                         \
        _Pragma("unroll")                                                      \
        for (int mf = 0; mf < 4; ++mf)                                         \
            _Pragma("unroll")                                                  \
            for (int nf = 0; nf < 8; ++nf)                                     \
                acc[mf][nf] = __builtin_amdgcn_mfma_f32_16x16x32_f16(          \
                    af[mf], bf[nf], acc[mf][nf], 0, 0, 0);                     \
        __builtin_amdgcn_s_setprio(0);                                         \
    }

    for (int kc = 0; kc < 18; kc += 2) {
        JITER_FULL(kc * 32,      Ash0, Bsh0, Ash1, Bsh1);
        JITER_FULL(kc * 32 + 32, Ash1, Bsh1, Ash0, Bsh0);
    }
    JITER_FULL(576, Ash0, Bsh0, Ash1, Bsh1);   // computes k=576, stages 608
    JITER_LAST(Ash1, Bsh1);                    // computes k=608

#undef JITER_FULL
#undef JITER_LAST

    // ---- epilogue: + bias, store fp32 ----
    float bv[8];
#pragma unroll
    for (int nf = 0; nf < 8; ++nf)
        bv[nf] = bias[n0 + wn * 128 + nf * 16 + lr];

#pragma unroll
    for (int mf = 0; mf < 4; ++mf) {
#pragma unroll
        for (int rr = 0; rr < 4; ++rr) {
            const int row = m0 + wm * 64 + mf * 16 + lk * 4 + rr;
            float* orow = out + (size_t)row * 1024 + n0 + wn * 128;
#pragma unroll
            for (int nf = 0; nf < 8; ++nf)
                orow[nf * 16 + lr] = acc[mf][nf][rr] + bv[nf];
        }
    }
}

// ---------------------------------------------------------------------------
extern "C" void kernel_launch(void* const* d_in, const int* in_sizes, int n_in,
                              void* d_out, int out_size, void* d_ws, size_t ws_size,
                              hipStream_t stream) {
    const float* enc   = (const float*)d_in[0];   // [8,256,512]
    const float* pred  = (const float*)d_in[1];   // [8,64,512]
    const float* Wenc  = (const float*)d_in[2];   // [640,512]
    const float* Wpred = (const float*)d_in[3];   // [640,512]
    const float* Wout  = (const float*)d_in[4];   // [1024,640]
    const float* bout  = (const float*)d_in[5];   // [1024]

    float*     fg = (float*)d_ws;                              // 2560*640 fp32
    _Float16*  Wh = (_Float16*)((char*)d_ws + 2560 * 640 * 4); // 1024*640 fp16

    fg_kernel<<<400, 256, 0, stream>>>(enc, pred, Wenc, Wpred, fg);
    wconv_kernel<<<320, 256, 0, stream>>>(Wout, Wh);
    joint_kernel<<<2048, 512, 0, stream>>>(fg, Wh, bout, (float*)d_out);
}